// Round 2
// baseline (365.742 us; speedup 1.0000x reference)
//
#include <hip/hip_runtime.h>

typedef unsigned short u16;
typedef __bf16 bf16x8 __attribute__((ext_vector_type(8)));
typedef float f32x4 __attribute__((ext_vector_type(4)));
typedef u16 u16x8 __attribute__((ext_vector_type(8)));

constexpr int T_DIM = 4096;
constexpr int DH    = 256;

__device__ __forceinline__ u16 f2bf(float f) {
    union { float f; unsigned u; } v; v.f = f;
    return (u16)((v.u + 0x7FFFu + ((v.u >> 16) & 1u)) >> 16);
}

// ---------------- prep: Wt[j][k] = bf16(W[k][j]) ----------------
__global__ __launch_bounds__(256) void prep_w(
    const float* __restrict__ Wq, const float* __restrict__ Wk,
    const float* __restrict__ Wv, const float* __restrict__ Wo,
    u16* __restrict__ Wqt, u16* __restrict__ Wkt,
    u16* __restrict__ Wvt, u16* __restrict__ Wot)
{
    int idx = blockIdx.x * 256 + threadIdx.x;   // 65536 outputs, [j][k] row-major
    int j = idx >> 8, k = idx & 255;
    int s = k * 256 + j;
    Wqt[idx] = f2bf(Wq[s]);
    Wkt[idx] = f2bf(Wk[s]);
    Wvt[idx] = f2bf(Wv[s]);
    Wot[idx] = f2bf(Wo[s]);
}

// ---------------- QKV projection: 64 rows/block, 4 waves ----------------
__global__ __launch_bounds__(256) void qkv_kernel(
    const float* __restrict__ x,
    const u16* __restrict__ Wqt, const u16* __restrict__ Wkt, const u16* __restrict__ Wvt,
    const float* __restrict__ bq, const float* __restrict__ bk, const float* __restrict__ bv,
    u16* __restrict__ Qg, u16* __restrict__ Kg, u16* __restrict__ Vtg)
{
    __shared__ u16 xlds[64 * DH];          // 32KB, XOR-swizzled rows of 512B
    char* xl = (char*)xlds;
    const int tid = threadIdx.x;
    const long row0 = (long)blockIdx.x * 64;

    #pragma unroll
    for (int i = 0; i < 8; ++i) {
        int sid  = tid + i * 256;          // 2048 slots of 16B (bf16)
        int row  = sid >> 5;
        int slot = sid & 31;
        const float* src = x + (row0 + row) * DH + slot * 8;
        float4 a  = *(const float4*)(src);
        float4 b2 = *(const float4*)(src + 4);
        u16x8 p;
        p[0] = f2bf(a.x);  p[1] = f2bf(a.y);  p[2] = f2bf(a.z);  p[3] = f2bf(a.w);
        p[4] = f2bf(b2.x); p[5] = f2bf(b2.y); p[6] = f2bf(b2.z); p[7] = f2bf(b2.w);
        *(u16x8*)(xl + row * 512 + ((slot * 16) ^ ((row & 7) << 4))) = p;
    }
    __syncthreads();

    const int w = tid >> 6, l = tid & 63;
    const int lr = l & 15, lh = l >> 4;
    const int arow = w * 16 + lr;

    bf16x8 af[8];                           // wave's A-fragments, reused for 3 targets
    #pragma unroll
    for (int ks = 0; ks < 8; ++ks)
        af[ks] = *(const bf16x8*)(xl + arow * 512 + ((ks * 64 + lh * 16) ^ ((arow & 7) << 4)));

    const u16*  Wt3[3] = { Wqt, Wkt, Wvt };
    const float* b3[3] = { bq, bk, bv };

    #pragma unroll
    for (int tgt = 0; tgt < 3; ++tgt) {
        f32x4 acc[16] = {};
        const u16* Wt = Wt3[tgt];
        #pragma unroll
        for (int ks = 0; ks < 8; ++ks) {
            bf16x8 a = af[ks];
            #pragma unroll
            for (int n = 0; n < 16; ++n) {
                bf16x8 bf = *(const bf16x8*)(Wt + (n * 16 + lr) * DH + ks * 32 + lh * 8);
                acc[n] = __builtin_amdgcn_mfma_f32_16x16x32_bf16(a, bf, acc[n], 0, 0, 0);
            }
        }
        const float* bias = b3[tgt];
        long grow = row0 + w * 16 + lh * 4;
        #pragma unroll
        for (int n = 0; n < 16; ++n) {
            int col = n * 16 + lr;
            float bb = bias[col];
            #pragma unroll
            for (int r = 0; r < 4; ++r) {
                u16 h = f2bf(acc[n][r] + bb);
                long g = grow + r;
                if (tgt == 0)      Qg[g * DH + col] = h;
                else if (tgt == 1) Kg[g * DH + col] = h;
                else {
                    long bb2 = g >> 12;               // batch (T=4096, blocks never straddle)
                    int  tt  = (int)(g & 4095);
                    Vtg[(bb2 * DH + col) * T_DIM + tt] = h;   // V stored transposed [b][d][t]
                }
            }
        }
    }
}

// ---------------- fused retention: per block 128 q-rows, 8 waves x 16 rows ----------------
__global__ __launch_bounds__(512) void retention_kernel(
    const u16* __restrict__ Qg, const u16* __restrict__ Kg, const u16* __restrict__ Vtg,
    const float* __restrict__ gamma, u16* __restrict__ Rg)
{
    __shared__ u16 klds[64 * DH];    // 32KB K tile; reused as per-wave P after barrier
    __shared__ u16 vlds[DH * 64];    // 32KB Vt tile  (total 64KB static)
    char* kl = (char*)klds;
    char* vl = (char*)vlds;
    const int tid = threadIdx.x;
    const int w = tid >> 6, l = tid & 63;
    const int lr = l & 15, lh = l >> 4;
    const int b  = blockIdx.x >> 5;               // 8 batches x 32 q-blocks
    const int q0 = (blockIdx.x & 31) * 128;

    bf16x8 qf[8];                                 // Q A-frags in registers for whole block
    {
        const char* qb = (const char*)(Qg + ((long)b * T_DIM + q0 + w * 16 + lr) * DH);
        #pragma unroll
        for (int ks = 0; ks < 8; ++ks)
            qf[ks] = *(const bf16x8*)(qb + ks * 64 + lh * 16);
    }

    f32x4 acc[16] = {};                           // retained [16 rows][256 cols] per wave

    for (int s0 = 0; s0 < T_DIM; s0 += 64) {
        __syncthreads();                          // prev-iter P/Vt reads finished
        {   // stage K tile [64][256] bf16, swizzled
            const char* kg = (const char*)(Kg + ((long)b * T_DIM + s0) * DH);
            #pragma unroll
            for (int i = 0; i < 4; ++i) {
                int sid = tid + i * 512;
                int row = sid >> 5, slot = sid & 31;
                u16x8 val = *(const u16x8*)(kg + row * 512 + slot * 16);
                *(u16x8*)(kl + row * 512 + ((slot * 16) ^ ((row & 7) << 4))) = val;
            }
        }
        {   // stage Vt tile [256][64] bf16, swizzled (128B rows)
            const char* vg = (const char*)(Vtg + (long)b * DH * T_DIM + s0);
            #pragma unroll
            for (int i = 0; i < 4; ++i) {
                int sid = tid + i * 512;
                int row = sid >> 3, slot = sid & 7;
                u16x8 val = *(const u16x8*)(vg + (long)row * (T_DIM * 2) + slot * 16);
                *(u16x8*)(vl + row * 128 + ((slot * 16) ^ ((row & 7) << 4))) = val;
            }
        }
        __syncthreads();

        // prefetch gamma (hides L3 latency under the S MFMAs)
        float gv[16];
        {
            const float* gp = gamma + (long)(q0 + w * 16 + lh * 4) * T_DIM + s0;
            #pragma unroll
            for (int n = 0; n < 4; ++n)
                #pragma unroll
                for (int r = 0; r < 4; ++r)
                    gv[n * 4 + r] = gp[r * T_DIM + n * 16 + lr];
        }

        // S = Q K^T : wave's 16 rows x 64 s-cols
        f32x4 sacc[4] = {};
        #pragma unroll
        for (int ks = 0; ks < 8; ++ks) {
            bf16x8 a = qf[ks];
            #pragma unroll
            for (int n = 0; n < 4; ++n) {
                int srow = n * 16 + lr;
                bf16x8 bf = *(const bf16x8*)(kl + srow * 512 + ((ks * 64 + lh * 16) ^ ((srow & 7) << 4)));
                sacc[n] = __builtin_amdgcn_mfma_f32_16x16x32_bf16(a, bf, sacc[n], 0, 0, 0);
            }
        }

        // gate: P = gamma .* S  (C layout: row=lh*4+r, col=n*16+lr), pack bf16
        u16 pv[16];
        #pragma unroll
        for (int n = 0; n < 4; ++n)
            #pragma unroll
            for (int r = 0; r < 4; ++r)
                pv[n * 4 + r] = f2bf(gv[n * 4 + r] * sacc[n][r]);

        __syncthreads();                          // all waves done reading K tile

        // write per-wave P [16][64] bf16 into K region (2KB/wave), swizzled
        char* pb = kl + w * 2048;
        #pragma unroll
        for (int n = 0; n < 4; ++n) {
            int cb = (n * 16 + lr) * 2;
            #pragma unroll
            for (int r = 0; r < 4; ++r) {
                int pr = lh * 4 + r;
                *(u16*)(pb + pr * 128 + (cb ^ ((pr & 7) << 4))) = pv[n * 4 + r];
            }
        }

        // retained += P @ V  (A=P from LDS, B=Vt rows)
        #pragma unroll
        for (int k2 = 0; k2 < 2; ++k2) {
            bf16x8 a = *(const bf16x8*)(pb + lr * 128 + ((k2 * 64 + lh * 16) ^ ((lr & 7) << 4)));
            #pragma unroll
            for (int n = 0; n < 16; ++n) {
                int vrow = n * 16 + lr;
                bf16x8 bf = *(const bf16x8*)(vl + vrow * 128 + ((k2 * 64 + lh * 16) ^ ((vrow & 7) << 4)));
                acc[n] = __builtin_amdgcn_mfma_f32_16x16x32_bf16(a, bf, acc[n], 0, 0, 0);
            }
        }
    }

    // store R as bf16 [B*T][256]
    long grow = (long)b * T_DIM + q0 + w * 16 + lh * 4;
    #pragma unroll
    for (int n = 0; n < 16; ++n) {
        int col = n * 16 + lr;
        #pragma unroll
        for (int r = 0; r < 4; ++r)
            Rg[(grow + r) * DH + col] = f2bf(acc[n][r]);
    }
}

// ---------------- output projection + PReLU ----------------
__global__ __launch_bounds__(256) void out_kernel(
    const u16* __restrict__ Rg, const u16* __restrict__ Wot,
    const float* __restrict__ bo, const float* __restrict__ pa,
    float* __restrict__ out)
{
    __shared__ u16 rlds[64 * DH];
    char* rl = (char*)rlds;
    const int tid = threadIdx.x;
    const long row0 = (long)blockIdx.x * 64;
    #pragma unroll
    for (int i = 0; i < 8; ++i) {
        int sid = tid + i * 256;
        int row = sid >> 5, slot = sid & 31;
        u16x8 v = *(const u16x8*)((const char*)(Rg + (row0 + row) * DH) + slot * 16);
        *(u16x8*)(rl + row * 512 + ((slot * 16) ^ ((row & 7) << 4))) = v;
    }
    __syncthreads();
    const int w = tid >> 6, l = tid & 63;
    const int lr = l & 15, lh = l >> 4;
    const int arow = w * 16 + lr;
    f32x4 acc[16] = {};
    #pragma unroll
    for (int ks = 0; ks < 8; ++ks) {
        bf16x8 a = *(const bf16x8*)(rl + arow * 512 + ((ks * 64 + lh * 16) ^ ((arow & 7) << 4)));
        #pragma unroll
        for (int n = 0; n < 16; ++n) {
            bf16x8 bf = *(const bf16x8*)(Wot + (n * 16 + lr) * DH + ks * 32 + lh * 8);
            acc[n] = __builtin_amdgcn_mfma_f32_16x16x32_bf16(a, bf, acc[n], 0, 0, 0);
        }
    }
    const float alpha = pa[0];
    long grow = row0 + w * 16 + lh * 4;
    #pragma unroll
    for (int n = 0; n < 16; ++n) {
        int col = n * 16 + lr;
        float bb = bo[col];
        #pragma unroll
        for (int r = 0; r < 4; ++r) {
            float y = acc[n][r] + bb;
            out[(grow + r) * DH + col] = (y >= 0.f) ? y : alpha * y;
        }
    }
}

extern "C" void kernel_launch(void* const* d_in, const int* in_sizes, int n_in,
                              void* d_out, int out_size, void* d_ws, size_t ws_size,
                              hipStream_t stream)
{
    const float* x     = (const float*)d_in[0];
    const float* gamma = (const float*)d_in[1];
    const float* Wq = (const float*)d_in[2];
    const float* bq = (const float*)d_in[3];
    const float* Wk = (const float*)d_in[4];
    const float* bk = (const float*)d_in[5];
    const float* Wv = (const float*)d_in[6];
    const float* bv = (const float*)d_in[7];
    const float* Wo = (const float*)d_in[8];
    const float* bo = (const float*)d_in[9];
    const float* pa = (const float*)d_in[10];
    float* out = (float*)d_out;

    char* ws = (char*)d_ws;
    const long SZ = 16777216L;                 // 8*4096*256 bf16 bytes
    u16* Wqt = (u16*)(ws);
    u16* Wkt = (u16*)(ws + 131072);
    u16* Wvt = (u16*)(ws + 262144);
    u16* Wot = (u16*)(ws + 393216);
    u16* Qg  = (u16*)(ws + 524288);
    u16* Kg  = (u16*)(ws + 524288 + SZ);
    u16* Vtg = (u16*)(ws + 524288 + 2 * SZ);
    u16* Rg  = (u16*)(ws + 524288 + 3 * SZ);

    hipLaunchKernelGGL(prep_w, dim3(256), dim3(256), 0, stream,
                       Wq, Wk, Wv, Wo, Wqt, Wkt, Wvt, Wot);
    hipLaunchKernelGGL(qkv_kernel, dim3(512), dim3(256), 0, stream,
                       x, Wqt, Wkt, Wvt, bq, bk, bv, Qg, Kg, Vtg);
    hipLaunchKernelGGL(retention_kernel, dim3(256), dim3(512), 0, stream,
                       Qg, Kg, Vtg, gamma, Rg);
    hipLaunchKernelGGL(out_kernel, dim3(512), dim3(256), 0, stream,
                       Rg, Wot, bo, pa, out);
}